// Round 6
// baseline (444.445 us; speedup 1.0000x reference)
//
#include <hip/hip_runtime.h>
#include <hip/hip_bf16.h>

#define N_NODES 20000
#define B 4
#define H 128
#define I_DIM 64
#define E_MAX 320000

// ---- all scratch in module-static device globals (no d_ws dependence) ----
__device__ int   g_cnt_src[N_NODES];
__device__ int   g_cnt_dst[N_NODES];
__device__ int   g_offsets[N_NODES + 1];
__device__ int   g_cursor[N_NODES];
__device__ int   g_csr[E_MAX];
__device__ float g_dn_src[N_NODES];
__device__ float g_dn_dst[N_NODES];
__device__ float g_xg[4 * B * H];
// batch-interleaved bf16 copy of h_prev: g_hs[n*H+h] = {bf16 h_prev[b][n][h], b=0..3}
__device__ uint2 g_hs[N_NODES * H];

// ---------------- zero the histograms ----------------
__global__ void zero_kernel() {
    int i = blockIdx.x * blockDim.x + threadIdx.x;
    if (i < N_NODES) {
        g_cnt_src[i] = 0;
        g_cnt_dst[i] = 0;
    }
}

// ---------------- int histograms of src and dst ----------------
__global__ void hist_kernel(const int* __restrict__ src, const int* __restrict__ dst, int E) {
    int e = blockIdx.x * blockDim.x + threadIdx.x;
    if (e < E) {
        atomicAdd(&g_cnt_src[src[e]], 1);
        atomicAdd(&g_cnt_dst[dst[e]], 1);
    }
}

// -------- single-block exclusive scan of cnt_dst -> offsets/cursor; dn factors --------
__global__ void scan_kernel() {
    __shared__ int sums[256];
    int t = threadIdx.x;
    const int CH = (N_NODES + 255) / 256;       // 79
    int lo = t * CH;
    int hi = lo + CH; if (hi > N_NODES) hi = N_NODES;
    int s = 0;
    for (int i = lo; i < hi; i++) s += g_cnt_dst[i];
    sums[t] = s;
    __syncthreads();
    if (t == 0) {
        int run = 0;
        for (int i = 0; i < 256; i++) { int v = sums[i]; sums[i] = run; run += v; }
        g_offsets[N_NODES] = run;               // total E
    }
    __syncthreads();
    int run = sums[t];
    for (int i = lo; i < hi; i++) {
        g_offsets[i] = run;
        g_cursor[i]  = run;
        run += g_cnt_dst[i];
        g_dn_src[i] = rsqrtf(fmaxf((float)g_cnt_src[i], 1.0f));
        g_dn_dst[i] = rsqrtf(fmaxf((float)g_cnt_dst[i], 1.0f));
    }
}

// ---------------- CSR build: bucket src ids by dst ----------------
__global__ void csr_kernel(const int* __restrict__ src, const int* __restrict__ dst, int E) {
    int e = blockIdx.x * blockDim.x + threadIdx.x;
    if (e < E) {
        int pos = atomicAdd(&g_cursor[dst[e]], 1);
        g_csr[pos] = src[e];
    }
}

// -------- pack h_prev into batch-interleaved bf16 (independent of graph) --------
__global__ void pack_kernel(const float* __restrict__ h_prev) {
    int i = blockIdx.x * blockDim.x + threadIdx.x;   // (n*H + h)
    if (i >= N_NODES * H) return;
    const long stride = (long)N_NODES * H;
    float v0 = h_prev[i];
    float v1 = h_prev[i + stride];
    float v2 = h_prev[i + 2 * stride];
    float v3 = h_prev[i + 3 * stride];
    __hip_bfloat162 p01 = __float22bfloat162_rn(make_float2(v0, v1));
    __hip_bfloat162 p23 = __float22bfloat162_rn(make_float2(v2, v3));
    uint2 w;
    w.x = *reinterpret_cast<unsigned int*>(&p01);
    w.y = *reinterpret_cast<unsigned int*>(&p23);
    g_hs[i] = w;
}

// ---------------- xg[g][b][h] = x[b,:] @ W_g + b_g  (fp32) ----------------
__global__ void xgate_kernel(const float* __restrict__ x,
                             const float* __restrict__ Wi, const float* __restrict__ bi,
                             const float* __restrict__ Wf, const float* __restrict__ bf_,
                             const float* __restrict__ Wo, const float* __restrict__ bo,
                             const float* __restrict__ Wc, const float* __restrict__ bc) {
    int g = blockIdx.x >> 2;   // gate 0..3 (i,f,o,c)
    int b = blockIdx.x & 3;
    int h = threadIdx.x;
    const float* W;
    const float* bb;
    switch (g) {
        case 0: W = Wi; bb = bi; break;
        case 1: W = Wf; bb = bf_; break;
        case 2: W = Wo; bb = bo; break;
        default: W = Wc; bb = bc; break;
    }
    float acc = bb[h];
    for (int i = 0; i < I_DIM; i++)
        acc += x[b * I_DIM + i] * W[i * H + h];
    g_xg[(g * B + b) * H + h] = acc;
}

// ------- fused: CSR gather (bf16 table) + dn scaling + Wg matvec + gates + LSTM ---------
__global__ __launch_bounds__(128)
void fused_kernel(const float* __restrict__ Wg, const float* __restrict__ bg,
                  const float* __restrict__ c_prev,
                  float* __restrict__ out_h, float* __restrict__ out_c) {
    int n = blockIdx.x;
    int h = threadIdx.x;
    int beg = g_offsets[n];
    int end = g_offsets[n + 1];

    float a0 = 0.f, a1 = 0.f, a2 = 0.f, a3 = 0.f;
    for (int j = beg; j < end; j++) {
        int s = g_csr[j];                      // wave-uniform (broadcast)
        float sc = g_dn_src[s];                // wave-uniform
        uint2 w = g_hs[s * H + h];             // 8B/lane: all 4 batches, bf16
        __hip_bfloat162 p01 = *reinterpret_cast<__hip_bfloat162*>(&w.x);
        __hip_bfloat162 p23 = *reinterpret_cast<__hip_bfloat162*>(&w.y);
        float2 f01 = __bfloat1622float2(p01);
        float2 f23 = __bfloat1622float2(p23);
        a0 += f01.x * sc;
        a1 += f01.y * sc;
        a2 += f23.x * sc;
        a3 += f23.y * sc;
    }
    float dd = g_dn_dst[n];

    __shared__ float4 arow4[H];
    arow4[h] = make_float4(a0 * dd, a1 * dd, a2 * dd, a3 * dd);
    __syncthreads();

    float g0 = 0.f, g1 = 0.f, g2 = 0.f, g3 = 0.f;
#pragma unroll 8
    for (int k = 0; k < H; k++) {
        float w = Wg[k * H + h];               // coalesced, L1/L2-resident
        float4 a = arow4[k];                   // one ds_read_b128, broadcast
        g0 += a.x * w;
        g1 += a.y * w;
        g2 += a.z * w;
        g3 += a.w * w;
    }
    float bgh = bg[h];

    const long stride = (long)N_NODES * H;
    float gh_arr[B] = {g0 + bgh, g1 + bgh, g2 + bgh, g3 + bgh};
#pragma unroll
    for (int b = 0; b < B; b++) {
        float gh = gh_arr[b];
        float xi = g_xg[(0 * B + b) * H + h];
        float xf = g_xg[(1 * B + b) * H + h];
        float xo = g_xg[(2 * B + b) * H + h];
        float xc = g_xg[(3 * B + b) * H + h];

        float it = 1.f / (1.f + expf(-(xi + gh)));
        float ft = 1.f / (1.f + expf(-(xf + gh)));
        float ot = 1.f / (1.f + expf(-(xo + gh)));
        float ct = tanhf(xc + gh);

        long idx = (long)b * stride + (long)n * H + h;
        float cp = c_prev[idx];
        float c  = ft * cp + it * ct;
        float ho = ot * tanhf(c);

        out_h[idx] = ho;
        out_c[idx] = c;
    }
}

extern "C" void kernel_launch(void* const* d_in, const int* in_sizes, int n_in,
                              void* d_out, int out_size, void* d_ws, size_t ws_size,
                              hipStream_t stream) {
    const float* x      = (const float*)d_in[0];
    const float* h_prev = (const float*)d_in[1];
    const float* c_prev = (const float*)d_in[2];
    const int* src = (const int*)d_in[3];
    const int* dst = (const int*)d_in[4];
    const float* Wi = (const float*)d_in[5];
    const float* bi = (const float*)d_in[6];
    const float* Wf = (const float*)d_in[7];
    const float* bf_ = (const float*)d_in[8];
    const float* Wo = (const float*)d_in[9];
    const float* bo = (const float*)d_in[10];
    const float* Wc = (const float*)d_in[11];
    const float* bc = (const float*)d_in[12];
    const float* Wg = (const float*)d_in[13];
    const float* bg = (const float*)d_in[14];

    int E = in_sizes[3];
    if (E > E_MAX) E = E_MAX;   // static scratch bound (setup fixes E=320000)

    zero_kernel<<<(N_NODES + 255) / 256, 256, 0, stream>>>();
    hist_kernel<<<(E + 255) / 256, 256, 0, stream>>>(src, dst, E);
    scan_kernel<<<1, 256, 0, stream>>>();
    csr_kernel<<<(E + 255) / 256, 256, 0, stream>>>(src, dst, E);
    pack_kernel<<<(N_NODES * H + 255) / 256, 256, 0, stream>>>(h_prev);
    xgate_kernel<<<16, H, 0, stream>>>(x, Wi, bi, Wf, bf_, Wo, bo, Wc, bc);

    float* out_h = (float*)d_out;
    float* out_c = out_h + (long)B * N_NODES * H;
    fused_kernel<<<N_NODES, H, 0, stream>>>(Wg, bg, c_prev, out_h, out_c);
}

// Round 7
// 376.189 us; speedup vs baseline: 1.1814x; 1.1814x over previous
//
#include <hip/hip_runtime.h>
#include <hip/hip_bf16.h>

#define N_NODES 20000
#define B 4
#define H 128
#define I_DIM 64
#define E_MAX 320000
#define K_PART 64           // partition blocks for counting sort
#define NW (N_NODES / 2)    // packed 16-bit counter words (N_NODES even)

// ---- all scratch in module-static device globals (no d_ws dependence) ----
__device__ int   g_cnt2_dst[K_PART * N_NODES];  // per-block partials -> exclusive col prefix
__device__ int   g_cnt2_src[K_PART * N_NODES];
__device__ int   g_tot_dst[N_NODES];
__device__ int   g_offsets[N_NODES + 1];
__device__ int   g_csr[E_MAX];
__device__ float g_dn_src[N_NODES];
__device__ float g_dn_dst[N_NODES];
__device__ float g_xg[4 * B * H];
// batch-interleaved bf16 copy of h_prev: g_hs[n*H+h] = {bf16 h_prev[b][n][h], b=0..3}
__device__ uint2 g_hs[N_NODES * H];

// ---- phase 1: per-block LDS histograms (no global atomics) ----
__global__ __launch_bounds__(256)
void part_hist_kernel(const int* __restrict__ src, const int* __restrict__ dst,
                      int E, int chunk) {
    __shared__ unsigned int h16[NW];          // 40 KB, two 16-bit counters per word
    int k = blockIdx.x;
    int t = threadIdx.x;
    for (int i = t; i < NW; i += 256) h16[i] = 0u;
    __syncthreads();
    int beg = k * chunk;
    int end = beg + chunk; if (end > E) end = E;
    for (int e = beg + t; e < end; e += 256) {
        int d = dst[e];
        atomicAdd(&h16[d >> 1], 1u << ((d & 1) * 16));
    }
    __syncthreads();
    for (int i = t; i < NW; i += 256) {
        unsigned int w = h16[i];
        g_cnt2_dst[k * N_NODES + 2 * i]     = (int)(w & 0xffffu);
        g_cnt2_dst[k * N_NODES + 2 * i + 1] = (int)(w >> 16);
    }
    __syncthreads();
    for (int i = t; i < NW; i += 256) h16[i] = 0u;
    __syncthreads();
    for (int e = beg + t; e < end; e += 256) {
        int s = src[e];
        atomicAdd(&h16[s >> 1], 1u << ((s & 1) * 16));
    }
    __syncthreads();
    for (int i = t; i < NW; i += 256) {
        unsigned int w = h16[i];
        g_cnt2_src[k * N_NODES + 2 * i]     = (int)(w & 0xffffu);
        g_cnt2_src[k * N_NODES + 2 * i + 1] = (int)(w >> 16);
    }
}

// ---- phase 2a: column scan along k (coalesced across n) + totals + dn ----
__global__ void colscan_kernel() {
    int n = blockIdx.x * blockDim.x + threadIdx.x;
    if (n >= N_NODES) return;
    int run = 0;
#pragma unroll 4
    for (int k = 0; k < K_PART; k++) {
        int idx = k * N_NODES + n;
        int v = g_cnt2_dst[idx];
        g_cnt2_dst[idx] = run;                // exclusive prefix of dst counts along k
        run += v;
    }
    g_tot_dst[n] = run;
    int rs = 0;
#pragma unroll 4
    for (int k = 0; k < K_PART; k++) rs += g_cnt2_src[k * N_NODES + n];
    g_dn_dst[n] = rsqrtf(fmaxf((float)run, 1.0f));
    g_dn_src[n] = rsqrtf(fmaxf((float)rs,  1.0f));
}

// ---- phase 2b: single-block exclusive scan of tot_dst -> offsets ----
__global__ void scan_kernel() {
    __shared__ int sums[256];
    int t = threadIdx.x;
    const int CH = (N_NODES + 255) / 256;     // 79
    int lo = t * CH;
    int hi = lo + CH; if (hi > N_NODES) hi = N_NODES;
    int s = 0;
    for (int i = lo; i < hi; i++) s += g_tot_dst[i];
    sums[t] = s;
    __syncthreads();
    if (t == 0) {
        int run = 0;
        for (int i = 0; i < 256; i++) { int v = sums[i]; sums[i] = run; run += v; }
        g_offsets[N_NODES] = run;
    }
    __syncthreads();
    int run = sums[t];
    for (int i = lo; i < hi; i++) {
        g_offsets[i] = run;
        run += g_tot_dst[i];
    }
}

// ---- phase 3: placement via LDS cursor (rank within (block,dst)) ----
__global__ __launch_bounds__(256)
void place_kernel(const int* __restrict__ src, const int* __restrict__ dst,
                  int E, int chunk) {
    __shared__ unsigned int cur16[NW];        // cursor = col-prefix base, 16-bit packed
    int k = blockIdx.x;
    int t = threadIdx.x;
    for (int i = t; i < NW; i += 256) {
        unsigned int lo = (unsigned int)g_cnt2_dst[k * N_NODES + 2 * i];
        unsigned int hi = (unsigned int)g_cnt2_dst[k * N_NODES + 2 * i + 1];
        cur16[i] = lo | (hi << 16);
    }
    __syncthreads();
    int beg = k * chunk;
    int end = beg + chunk; if (end > E) end = E;
    for (int e = beg + t; e < end; e += 256) {
        int d = dst[e];
        int s = src[e];
        unsigned int old = atomicAdd(&cur16[d >> 1], 1u << ((d & 1) * 16));
        int rank = (int)((old >> ((d & 1) * 16)) & 0xffffu);
        g_csr[g_offsets[d] + rank] = s;       // offsets: 80 KB table, L2-hot gather
    }
}

// -------- pack h_prev into batch-interleaved bf16 (independent of graph) --------
__global__ void pack_kernel(const float* __restrict__ h_prev) {
    int i = blockIdx.x * blockDim.x + threadIdx.x;   // (n*H + h)
    if (i >= N_NODES * H) return;
    const long stride = (long)N_NODES * H;
    float v0 = h_prev[i];
    float v1 = h_prev[i + stride];
    float v2 = h_prev[i + 2 * stride];
    float v3 = h_prev[i + 3 * stride];
    __hip_bfloat162 p01 = __float22bfloat162_rn(make_float2(v0, v1));
    __hip_bfloat162 p23 = __float22bfloat162_rn(make_float2(v2, v3));
    uint2 w;
    w.x = *reinterpret_cast<unsigned int*>(&p01);
    w.y = *reinterpret_cast<unsigned int*>(&p23);
    g_hs[i] = w;
}

// ---------------- xg[g][b][h] = x[b,:] @ W_g + b_g  (fp32) ----------------
__global__ void xgate_kernel(const float* __restrict__ x,
                             const float* __restrict__ Wi, const float* __restrict__ bi,
                             const float* __restrict__ Wf, const float* __restrict__ bf_,
                             const float* __restrict__ Wo, const float* __restrict__ bo,
                             const float* __restrict__ Wc, const float* __restrict__ bc) {
    int g = blockIdx.x >> 2;   // gate 0..3 (i,f,o,c)
    int b = blockIdx.x & 3;
    int h = threadIdx.x;
    const float* W;
    const float* bb;
    switch (g) {
        case 0: W = Wi; bb = bi; break;
        case 1: W = Wf; bb = bf_; break;
        case 2: W = Wo; bb = bo; break;
        default: W = Wc; bb = bc; break;
    }
    float acc = bb[h];
    for (int i = 0; i < I_DIM; i++)
        acc += x[b * I_DIM + i] * W[i * H + h];
    g_xg[(g * B + b) * H + h] = acc;
}

// ------- fused: CSR gather (bf16 table) + dn scaling + Wg matvec + gates + LSTM ---------
__global__ __launch_bounds__(128)
void fused_kernel(const float* __restrict__ Wg, const float* __restrict__ bg,
                  const float* __restrict__ c_prev,
                  float* __restrict__ out_h, float* __restrict__ out_c) {
    int n = blockIdx.x;
    int h = threadIdx.x;
    int beg = g_offsets[n];
    int end = g_offsets[n + 1];

    float a0 = 0.f, a1 = 0.f, a2 = 0.f, a3 = 0.f;
    for (int j = beg; j < end; j++) {
        int s = g_csr[j];                      // wave-uniform (broadcast)
        float sc = g_dn_src[s];                // wave-uniform
        uint2 w = g_hs[s * H + h];             // 8B/lane: all 4 batches, bf16
        __hip_bfloat162 p01 = *reinterpret_cast<__hip_bfloat162*>(&w.x);
        __hip_bfloat162 p23 = *reinterpret_cast<__hip_bfloat162*>(&w.y);
        float2 f01 = __bfloat1622float2(p01);
        float2 f23 = __bfloat1622float2(p23);
        a0 += f01.x * sc;
        a1 += f01.y * sc;
        a2 += f23.x * sc;
        a3 += f23.y * sc;
    }
    float dd = g_dn_dst[n];

    __shared__ float4 arow4[H];
    arow4[h] = make_float4(a0 * dd, a1 * dd, a2 * dd, a3 * dd);
    __syncthreads();

    float g0 = 0.f, g1 = 0.f, g2 = 0.f, g3 = 0.f;
#pragma unroll 8
    for (int k = 0; k < H; k++) {
        float w = Wg[k * H + h];               // coalesced, L1/L2-resident
        float4 a = arow4[k];                   // one ds_read_b128, broadcast
        g0 += a.x * w;
        g1 += a.y * w;
        g2 += a.z * w;
        g3 += a.w * w;
    }
    float bgh = bg[h];

    const long stride = (long)N_NODES * H;
    float gh_arr[B] = {g0 + bgh, g1 + bgh, g2 + bgh, g3 + bgh};
#pragma unroll
    for (int b = 0; b < B; b++) {
        float gh = gh_arr[b];
        float xi = g_xg[(0 * B + b) * H + h];
        float xf = g_xg[(1 * B + b) * H + h];
        float xo = g_xg[(2 * B + b) * H + h];
        float xc = g_xg[(3 * B + b) * H + h];

        float it = 1.f / (1.f + expf(-(xi + gh)));
        float ft = 1.f / (1.f + expf(-(xf + gh)));
        float ot = 1.f / (1.f + expf(-(xo + gh)));
        float ct = tanhf(xc + gh);

        long idx = (long)b * stride + (long)n * H + h;
        float cp = c_prev[idx];
        float c  = ft * cp + it * ct;
        float ho = ot * tanhf(c);

        out_h[idx] = ho;
        out_c[idx] = c;
    }
}

extern "C" void kernel_launch(void* const* d_in, const int* in_sizes, int n_in,
                              void* d_out, int out_size, void* d_ws, size_t ws_size,
                              hipStream_t stream) {
    const float* x      = (const float*)d_in[0];
    const float* h_prev = (const float*)d_in[1];
    const float* c_prev = (const float*)d_in[2];
    const int* src = (const int*)d_in[3];
    const int* dst = (const int*)d_in[4];
    const float* Wi = (const float*)d_in[5];
    const float* bi = (const float*)d_in[6];
    const float* Wf = (const float*)d_in[7];
    const float* bf_ = (const float*)d_in[8];
    const float* Wo = (const float*)d_in[9];
    const float* bo = (const float*)d_in[10];
    const float* Wc = (const float*)d_in[11];
    const float* bc = (const float*)d_in[12];
    const float* Wg = (const float*)d_in[13];
    const float* bg = (const float*)d_in[14];

    int E = in_sizes[3];
    if (E > E_MAX) E = E_MAX;   // static scratch bound (setup fixes E=320000)
    int chunk = (E + K_PART - 1) / K_PART;

    part_hist_kernel<<<K_PART, 256, 0, stream>>>(src, dst, E, chunk);
    colscan_kernel<<<(N_NODES + 255) / 256, 256, 0, stream>>>();
    scan_kernel<<<1, 256, 0, stream>>>();
    place_kernel<<<K_PART, 256, 0, stream>>>(src, dst, E, chunk);
    pack_kernel<<<(N_NODES * H + 255) / 256, 256, 0, stream>>>(h_prev);
    xgate_kernel<<<16, H, 0, stream>>>(x, Wi, bi, Wf, bf_, Wo, bo, Wc, bc);

    float* out_h = (float*)d_out;
    float* out_c = out_h + (long)B * N_NODES * H;
    fused_kernel<<<N_NODES, H, 0, stream>>>(Wg, bg, c_prev, out_h, out_c);
}